// Round 1
// baseline (158.600 us; speedup 1.0000x reference)
//
#include <hip/hip_runtime.h>
#include <math.h>

// Problem constants (from reference)
#define NB      2048        // batch
#define DIM     256         // input dim
#define SC6     192         // S*6 = 32 splines * 6 params
#define CV      128         // canvas size
#define NT      50          // samples along curve
#define CWORDS  (CV * CV / 4)   // 4096 u8-packed words per canvas
// W_STAMP = -0.07, BG = 0.3, SCALE = 1e-4

// log_prob per batch = 192*( -ln(1e-4) - 0.5*ln(2*pi) )  (raw == mu exactly)
// entropy  per batch = 192*( 0.5 + 0.5*ln(2*pi) + ln(1e-4) )
#define LPV  (1591.9491530441301f)
#define ENV  (-1495.9491530441301f)

// Output layout (flat, return order): sketch | log_prob | entropy | sample
#define SKETCH_N   ((size_t)NB * CV * CV)     // 33,554,432
#define LP_OFF     (SKETCH_N)
#define ENT_OFF    (LP_OFF + NB)
#define SAMPLE_OFF (ENT_OFF + NB)

typedef float vfloat4 __attribute__((ext_vector_type(4)));

// Workgroup barrier waiting ONLY on LDS ops (lgkmcnt), not global stores —
// __syncthreads() would emit s_waitcnt vmcnt(0) and drain epilogue stores on
// the critical path. All cross-phase deps here are LDS-only.
__device__ __forceinline__ void barrier_lds_only() {
    asm volatile("s_waitcnt lgkmcnt(0)\n\ts_barrier" ::: "memory");
}

// ---------------------------------------------------------------------------
// Restructured: ONE batch per 256-thread block, grid = 2048.
//   - 18.7 KB LDS/block (single canvas, no double-buffer, no re-zero)
//   - __launch_bounds__(256,6): target ~6 resident blocks/CU = 6 independent
//     4-wave barrier domains. Cross-block phase diversity (one block's paint/
//     GEMM overlaps another's epilogue stores) replaces the old intra-block
//     2-canvas pipeline, and keeps the HBM write stream continuous instead of
//     bursty (old: 2 lock-stepped 8-wave blocks/CU, grid-limited occupancy).
//   - Paint expression order is bit-identical to the previously passing
//     kernel; GEMM is reassociated into 2 f64 chains (flip prob ~1e-8/coord).
// ---------------------------------------------------------------------------
__global__ __launch_bounds__(256, 6) void fused_kernel(
    const float* __restrict__ x, const float* __restrict__ W,
    const float* __restrict__ bias, float* __restrict__ out)
{
    __shared__ unsigned int cnt[CWORDS];          // 16 KB u8-packed canvas
    __shared__ double sp[6][32];                  // SoA spline params * 128
    __shared__ double cfa[NT], cfb[NT], cfc[NT];  // (1-t)^2, 2(1-t)t, t^2

    const int b   = blockIdx.x;
    const int tid = threadIdx.x;

    if (tid < SC6) {
        // ---- gemm + sigmoid for this block's batch (f64, 2 chains) ----
        const int j = tid;
        const float* xb = x + (size_t)b * DIM;    // wave-uniform -> s_load
        double a0 = 0.0, a1 = 0.0;
        #pragma unroll 4
        for (int d = 0; d < DIM; d += 2) {
            a0 = fma((double)xb[d],     (double)W[d * SC6 + j],       a0);
            a1 = fma((double)xb[d + 1], (double)W[(d + 1) * SC6 + j], a1);
        }
        double s0 = 1.0 / (1.0 + exp(-((a0 + a1) + (double)bias[j])));
        out[SAMPLE_OFF + (size_t)b * SC6 + j] = (float)s0;
        sp[j % 6][j / 6] = s0 * 128.0;            // CANVAS scale, SoA
    } else {
        // ---- wave 3: zero canvas + coeff table + scalar outputs ----
        const int t2 = tid - SC6;                 // 0..63
        uint4* c4 = (uint4*)cnt;                  // 1024 uint4 words
        uint4 z = make_uint4(0u, 0u, 0u, 0u);
        #pragma unroll
        for (int w = t2; w < CWORDS / 4; w += 64) c4[w] = z;
        if (t2 < NT) {
            // np.linspace(0,1,50): t_k = k*fl64(1/49), endpoint forced to 1.0
            double t = (t2 == NT - 1) ? 1.0 : (double)t2 * (1.0 / 49.0);
            double u = 1.0 - t;
            cfa[t2] = u * u;                      // (1-t)**2
            cfb[t2] = (2.0 * u) * t;              // 2*(1-t)*t (ref assoc order)
            cfc[t2] = t * t;                      // t**2
        }
        if (t2 == 50) out[LP_OFF  + b] = LPV;
        if (t2 == 51) out[ENT_OFF + b] = ENV;
    }
    barrier_lds_only();

    // ---- paint: 32 splines x 50 points, stride 256 ----
    {
        // Thread's spline s = tid&31 is loop-invariant (i += 256 preserves
        // i&31): params hoisted to registers once per block.
        const int s = tid & 31;
        const double P0x = sp[0][s], P0y = sp[1][s];
        const double P1x = sp[2][s], P1y = sp[3][s];
        const double P2x = sp[4][s], P2y = sp[5][s];

        for (int i = tid; i < 32 * NT; i += 256) {
            int kraw = i >> 5;                    // 0..49
            int k    = (kraw * 9) % 50;           // bijection, spreads t per wave
            double a  = cfa[k];
            double bq = cfb[k];
            double c  = cfc[k];
            double px = a * P0x + bq * P1x + c * P2x;  // same op order as prior
            double py = a * P0y + bq * P1y + c * P2y;  // passing rounds
            int cx = (int)rint(px);               // round-half-even == np.round
            int cy = (int)rint(py);

            // clipped y-triple -> u8 increments for 1-2 adjacent 4-px words
            int y0 = min(max(cy - 1, 0), CV - 1);
            int y1 = min(max(cy,     0), CV - 1);
            int y2 = min(max(cy + 1, 0), CV - 1);
            int cb = y0 >> 2;                     // base word-column (0..31)
            unsigned incA = 1u << ((y0 & 3) << 3);
            unsigned incB = 0u;
            unsigned i1 = 1u << ((y1 & 3) << 3);
            unsigned i2 = 1u << ((y2 & 3) << 3);
            if ((y1 >> 2) == cb) incA += i1; else incB += i1;
            if ((y2 >> 2) == cb) incA += i2; else incB += i2;

            int x0 = min(max(cx - 1, 0), CV - 1);
            int x1 = min(max(cx,     0), CV - 1);
            int x2 = min(max(cx + 1, 0), CV - 1);
            int rows[3] = {x0, x1, x2};
            #pragma unroll
            for (int r = 0; r < 3; ++r) {
                int xi = rows[r];
                int base = xi << 5;
                // per-row rotated word layout spreads banks across rows
                atomicAdd(&cnt[base + ((cb + xi) & 31)], incA);
                if (incB) atomicAdd(&cnt[base + ((cb + 1 + xi) & 31)], incB);
            }
        }
    }
    barrier_lds_only();

    // ---- epilogue: clip(0.3 - 0.07*count, 0, 1), float4 stores ----
    // Single-use canvas: no re-zero needed (next batch = different block).
    vfloat4* ob = (vfloat4*)(out + (size_t)b * CV * CV);
    for (int w = tid; w < CWORDS; w += 256) {
        int xi  = w >> 5;                         // row
        int idx = (xi << 5) + (((w & 31) + xi) & 31);   // undo rotation
        unsigned v = cnt[idx];
        vfloat4 r;
        r.x = fminf(fmaxf(0.3f - 0.07f * (float)( v         & 255u), 0.0f), 1.0f);
        r.y = fminf(fmaxf(0.3f - 0.07f * (float)((v >>  8) & 255u), 0.0f), 1.0f);
        r.z = fminf(fmaxf(0.3f - 0.07f * (float)((v >> 16) & 255u), 0.0f), 1.0f);
        r.w = fminf(fmaxf(0.3f - 0.07f * (float)( v >> 24        ), 0.0f), 1.0f);
        ob[w] = r;                                // coalesced 16 B/lane
    }
}

extern "C" void kernel_launch(void* const* d_in, const int* in_sizes, int n_in,
                              void* d_out, int out_size, void* d_ws, size_t ws_size,
                              hipStream_t stream) {
    const float* x    = (const float*)d_in[0];   // [2048, 256]
    const float* W    = (const float*)d_in[1];   // [256, 192]
    const float* bias = (const float*)d_in[2];   // [192]
    float* out = (float*)d_out;

    fused_kernel<<<NB, 256, 0, stream>>>(x, W, bias, out);
}